// Round 4
// baseline (339.838 us; speedup 1.0000x reference)
//
#include <hip/hip_runtime.h>
#include <math.h>

#define SUPPORT 1.5f

// ---------------- hat basis ----------------
__device__ __forceinline__ void hat4(float u, float h[4]) {
#pragma unroll
    for (int j = 0; j < 4; ++j) {
        float c = -1.0f + j * (2.0f / 3.0f);
        h[j] = fmaxf(0.0f, 1.0f - fabsf(u - c) * 1.5f);
    }
}

// ---------------- per-edge RBF coefficients ----------------
template <bool NEG>
__global__ void coeff_kernel(const float2* __restrict__ pa, const int* __restrict__ ia,
                             const float2* __restrict__ pb, const int* __restrict__ ib,
                             float* __restrict__ out, int E) {
    int e = blockIdx.x * blockDim.x + threadIdx.x;
    if (e >= E) return;
    float2 A = pa[ia[e]];
    float2 B = pb[ib[e]];
    float rx = (A.x - B.x) / SUPPORT;
    float ry = (A.y - B.y) / SUPPORT;
    if (NEG) { rx = -rx; ry = -ry; }
    float dx = fminf(fmaxf(rx, -1.0f), 1.0f);
    float dy = fminf(fmaxf(ry, -1.0f), 1.0f);
    float r  = sqrtf(dx * dx + dy * dy) * 2.0f - 1.0f;
    float th = atan2f(dy, dx) / 3.14159265358979323846f;
    float hr[4], ht[4];
    hat4(r, hr);
    hat4(th, ht);
    float* o = out + (size_t)e * 16;
#pragma unroll
    for (int a = 0; a < 4; ++a)
#pragma unroll
        for (int b = 0; b < 4; ++b)
            o[a * 4 + b] = hr[a] * ht[b];
}

// ---------------- CSR offsets ----------------
__global__ void offsets_kernel(const int* __restrict__ sorted, int E,
                               int* __restrict__ off, int N1) {
    int i = blockIdx.x * blockDim.x + threadIdx.x;
    if (i >= N1) return;
    int lo = 0, hi = E;
    while (lo < hi) {
        int mid = (lo + hi) >> 1;
        if (sorted[mid] < i) lo = mid + 1; else hi = mid;
    }
    off[i] = lo;
}

// ---------------- layer 1 (small Cin, direct) ----------------
__global__ void layer1_kernel(const float* __restrict__ fluidFeats,
                              const float* __restrict__ boundaryFeats,
                              const float* __restrict__ fcW0, const float* __restrict__ fcb0,
                              const float* __restrict__ W0, const float* __restrict__ b0,
                              const float* __restrict__ W1, const float* __restrict__ b1,
                              const float* __restrict__ W2, const float* __restrict__ b2,
                              const float* __restrict__ W3, const float* __restrict__ b3,
                              const int* __restrict__ f_off, const int* __restrict__ fe_j,
                              const float* __restrict__ f_coeff,
                              const int* __restrict__ b_off, const int* __restrict__ be_b,
                              const float* __restrict__ b_coeff,
                              float* __restrict__ A1) {
    int n = blockIdx.x;
    int t = threadIdx.x;
    if (t >= 96) return;
    float val;
    if (t < 32) {
        val = fluidFeats[n * 2] * fcW0[t] + fluidFeats[n * 2 + 1] * fcW0[32 + t] + fcb0[t];
    } else if (t < 64) {
        int oc = t - 32;
        const float* W = (oc < 16) ? W0 : W1;
        int o16 = oc & 15;
        float s = (oc < 16) ? b0[o16] : b1[o16];
        int e1 = f_off[n + 1];
        for (int e = f_off[n]; e < e1; ++e) {
            const float* cf = f_coeff + (size_t)e * 16;
            int srcn = fe_j[e];
            float f0 = fluidFeats[srcn * 2], f1 = fluidFeats[srcn * 2 + 1];
            float acc = 0.0f;
#pragma unroll
            for (int k = 0; k < 16; ++k)
                acc += cf[k] * (f0 * W[(k * 2 + 0) * 16 + o16] + f1 * W[(k * 2 + 1) * 16 + o16]);
            s += acc;
        }
        val = s;
    } else {
        int oc = t - 64;
        const float* W = (oc < 16) ? W2 : W3;
        int o16 = oc & 15;
        float s = (oc < 16) ? b2[o16] : b3[o16];
        int e1 = b_off[n + 1];
        for (int e = b_off[n]; e < e1; ++e) {
            const float* cf = b_coeff + (size_t)e * 16;
            int srcn = be_b[e];
            float f0 = boundaryFeats[srcn * 3], f1 = boundaryFeats[srcn * 3 + 1],
                  f2 = boundaryFeats[srcn * 3 + 2];
            float acc = 0.0f;
#pragma unroll
            for (int k = 0; k < 16; ++k)
                acc += cf[k] * (f0 * W[(k * 3 + 0) * 16 + o16] +
                                f1 * W[(k * 3 + 1) * 16 + o16] +
                                f2 * W[(k * 3 + 2) * 16 + o16]);
            s += acc;
        }
        val = s;
    }
    A1[(size_t)n * 96 + t] = fmaxf(val, 0.0f);
}

// ---------------- prep: transpose weights into padded tiled layout ----------------
// ROWW = 276 (272 data words + 4 pad, 16B-aligned rows, stride 276 % 32 = 20 -> conflict-free)
// Wt[T*17664 + o*276 + rw] = (rw<272) ? Wsrc[j = T*272 + rw][o] : 0
// Wsrc col: o<32 -> WA[j*32+o], o>=32 -> WB[j*32+o-32]; j>=16*CIN -> fcW[(j-16CIN)*64+o]
__global__ void prep_kernel(const float* __restrict__ WA, const float* __restrict__ WB,
                            const float* __restrict__ fcW, float* __restrict__ Wt,
                            int CIN, int TILES) {
    int idx = blockIdx.x * 256 + threadIdx.x;
    int total = TILES * 17664;
    if (idx >= total) return;
    int T = idx / 17664;
    int r = idx - T * 17664;
    int o = r / 276;
    int rw = r - o * 276;
    float v = 0.0f;
    if (rw < 272) {
        int j = T * 272 + rw;
        int KC = 16 * CIN;
        if (j < KC) v = (o < 32) ? WA[(size_t)j * 32 + o] : WB[(size_t)j * 32 + (o - 32)];
        else        v = fcW[(size_t)(j - KC) * 64 + o];
    }
    Wt[idx] = v;
}

// ---------------- buildG: per-node outer-product accumulation ----------------
// G row (chunk-local) = [ sum_e coeff[e,k]*x[src,i] (k-major) | x_hat[n] ]  length KTOT=17*CIN
template <int CIN, bool RELU>
__global__ __launch_bounds__(256) void buildG_kernel(
    const float* __restrict__ X,
    const int* __restrict__ f_off, const int* __restrict__ fe_j,
    const float* __restrict__ f_coeff,
    float* __restrict__ G, int nodeBase) {
    constexpr int EPT = CIN / 16;      // 6 (CIN=96) or 4 (CIN=64)
    constexpr int KTOT = 17 * CIN;
    int n = nodeBase + blockIdx.x;
    int t = threadIdx.x;
    int k = t >> 4;
    int i0 = (t & 15) * EPT;
    float acc[EPT];
#pragma unroll
    for (int s = 0; s < EPT; ++s) acc[s] = 0.0f;
    int e0 = f_off[n], e1 = f_off[n + 1];
    for (int e = e0; e < e1; ++e) {
        int srcn = fe_j[e];
        float ck = f_coeff[(size_t)e * 16 + k];
        const float* xr = X + (size_t)srcn * CIN + i0;
#pragma unroll
        for (int s = 0; s < EPT; ++s) {
            float v = xr[s];
            if (RELU) v = fmaxf(v, 0.0f);
            acc[s] = fmaf(ck, v, acc[s]);
        }
    }
    float* grow = G + (size_t)blockIdx.x * KTOT;
#pragma unroll
    for (int s = 0; s < EPT; ++s) grow[k * CIN + i0 + s] = acc[s];
    if (t < CIN) {
        float v = X[(size_t)n * CIN + t];
        if (RELU) v = fmaxf(v, 0.0f);
        grow[16 * CIN + t] = v;
    }
}

// ---------------- GEMM: out[n][o] = G[n][:] @ Wt[o][:] + bias (+resid) (*1/128) ----------------
// 256 thr = 4 waves; wave handles 8 nodes; block = 32 nodes. W tile (64 rows x 276 padded
// words) staged in LDS; stride 276 spreads ds_read_b128 across all banks uniformly.
// G rows read via wave-uniform addresses (scalarizable broadcast loads).
template <int KTOT, int TILES, bool RESID, bool FINAL>
__global__ __launch_bounds__(256) void gemm_kernel(
    const float* __restrict__ G,       // chunk-local rows, stride KTOT
    const float* __restrict__ Wt,      // padded-tiled, TILES*17664
    const float* __restrict__ bA, const float* __restrict__ bB,
    const float* __restrict__ fcb,
    const float* __restrict__ Xres,
    float* __restrict__ OUT,
    int nodeBase, int cnt) {
    __shared__ float lds[64 * 276];
    const int t = threadIdx.x;
    const int o = t & 63;
    const int wv_id = __builtin_amdgcn_readfirstlane(t >> 6);
    const int lrow0 = blockIdx.x * 32 + wv_id * 8;

    const float* grow[8];
#pragma unroll
    for (int nn = 0; nn < 8; ++nn) {
        int lr = lrow0 + nn;
        if (lr > cnt - 1) lr = cnt - 1;
        grow[nn] = G + (size_t)lr * KTOT;
    }

    float acc[8];
#pragma unroll
    for (int nn = 0; nn < 8; ++nn) acc[nn] = 0.0f;

    for (int T = 0; T < TILES; ++T) {
        __syncthreads();
        const float4* src = (const float4*)(Wt + (size_t)T * 17664);
        float4* dst = (float4*)lds;
#pragma unroll
        for (int it = 0; it < 18; ++it) {
            int idx = it * 256 + t;
            if (idx < 4416) dst[idx] = src[idx];
        }
        __syncthreads();

        const float* lrow = lds + o * 276;
#pragma unroll 2
        for (int c = 0; c < 68; ++c) {
            float4 wv = *(const float4*)(lrow + (c << 2));
#pragma unroll
            for (int nn = 0; nn < 8; ++nn) {
                float4 g = *(const float4*)(grow[nn] + (c << 2));
                acc[nn] = fmaf(g.x, wv.x, acc[nn]);
                acc[nn] = fmaf(g.y, wv.y, acc[nn]);
                acc[nn] = fmaf(g.z, wv.z, acc[nn]);
                acc[nn] = fmaf(g.w, wv.w, acc[nn]);
            }
        }
#pragma unroll
        for (int nn = 0; nn < 8; ++nn) grow[nn] += 272;
    }

    float bias = ((o < 32) ? bA[o] : bB[o - 32]) + fcb[o];
#pragma unroll
    for (int nn = 0; nn < 8; ++nn) {
        int lr = lrow0 + nn;
        if (lr < cnt) {
            int node = nodeBase + lr;
            float s = acc[nn] + bias;
            if (RESID) s += Xres[(size_t)node * 64 + o];
            if (FINAL) s *= (1.0f / 128.0f);
            OUT[(size_t)node * 64 + o] = s;
        }
    }
}

// ---------------- fallback path (round-2 kernel, proven) ----------------
template <int CIN, bool RELU_IN, bool RESIDUAL, bool FINAL>
__global__ __launch_bounds__(256) void conv_layer_kernel(
    const float* __restrict__ X,
    const float* __restrict__ WA, const float* __restrict__ bA,
    const float* __restrict__ WB, const float* __restrict__ bB,
    const float* __restrict__ fcW, const float* __restrict__ fcb,
    const int* __restrict__ f_off, const int* __restrict__ fe_j,
    const float* __restrict__ f_coeff,
    float* __restrict__ OUT) {
    constexpr int NELEM = 16 * CIN;
    constexpr int EPT = NELEM / 256;
    constexpr int BATCH = 8;
    constexpr int CHUNK = NELEM / 4;

    __shared__ float x_lds[CIN];
    __shared__ float feat[BATCH][CIN];
    __shared__ float co[BATCH][16];
    __shared__ float Gs[NELEM];
    __shared__ float red[4][64];

    int n = blockIdx.x;
    int t = threadIdx.x;

    for (int i = t; i < CIN; i += 256) {
        float v = X[(size_t)n * CIN + i];
        if (RELU_IN) v = fmaxf(v, 0.0f);
        x_lds[i] = v;
    }

    float acc[EPT];
    int kk[EPT], ii[EPT];
#pragma unroll
    for (int s = 0; s < EPT; ++s) {
        acc[s] = 0.0f;
        int j = s * 256 + t;
        kk[s] = j / CIN;
        ii[s] = j - kk[s] * CIN;
    }

    int e0 = f_off[n], e1 = f_off[n + 1];
    for (int eb = e0; eb < e1; eb += BATCH) {
        int cnt = min(BATCH, e1 - eb);
        __syncthreads();
        for (int idx = t; idx < cnt * 16; idx += 256) {
            int b = idx >> 4, c = idx & 15;
            co[b][c] = f_coeff[(size_t)(eb + b) * 16 + c];
        }
        for (int idx = t; idx < cnt * CIN; idx += 256) {
            int b = idx / CIN, i = idx - b * CIN;
            int srcn = fe_j[eb + b];
            float v = X[(size_t)srcn * CIN + i];
            if (RELU_IN) v = fmaxf(v, 0.0f);
            feat[b][i] = v;
        }
        __syncthreads();
#pragma unroll
        for (int b = 0; b < BATCH; ++b) {
            if (b >= cnt) break;
#pragma unroll
            for (int s = 0; s < EPT; ++s) acc[s] += co[b][kk[s]] * feat[b][ii[s]];
        }
    }
    __syncthreads();
#pragma unroll
    for (int s = 0; s < EPT; ++s) Gs[s * 256 + t] = acc[s];
    __syncthreads();

    int o = t & 63;
    int chunk = t >> 6;
    const float* Wp = (o < 32) ? WA : WB;
    int oc = o & 31;
    int j0 = chunk * CHUNK;
    float p0 = 0.f, p1 = 0.f, p2 = 0.f, p3 = 0.f;
    for (int j = j0; j < j0 + CHUNK; j += 4) {
        p0 += Gs[j + 0] * Wp[(size_t)(j + 0) * 32 + oc];
        p1 += Gs[j + 1] * Wp[(size_t)(j + 1) * 32 + oc];
        p2 += Gs[j + 2] * Wp[(size_t)(j + 2) * 32 + oc];
        p3 += Gs[j + 3] * Wp[(size_t)(j + 3) * 32 + oc];
    }
    red[chunk][o] = ((p0 + p1) + (p2 + p3));
    __syncthreads();
    if (t < 64) {
        float s = red[0][o] + red[1][o] + red[2][o] + red[3][o];
        s += (o < 32) ? bA[oc] : bB[oc];
        float fcv = fcb[o];
        for (int i = 0; i < CIN; ++i) fcv += x_lds[i] * fcW[i * 64 + o];
        s += fcv;
        if (RESIDUAL) s += X[(size_t)n * 64 + o];
        if (FINAL) s *= (1.0f / 128.0f);
        OUT[(size_t)n * 64 + o] = s;
    }
}

extern "C" void kernel_launch(void* const* d_in, const int* in_sizes, int n_in,
                              void* d_out, int out_size, void* d_ws, size_t ws_size,
                              hipStream_t stream) {
    const float* fluidPos      = (const float*)d_in[0];
    const float* boundaryPos   = (const float*)d_in[1];
    const float* fluidFeats    = (const float*)d_in[2];
    const float* boundaryFeats = (const float*)d_in[3];
    const int* fe_i = (const int*)d_in[4];
    const int* fe_j = (const int*)d_in[5];
    const int* be_f = (const int*)d_in[6];
    const int* be_b = (const int*)d_in[7];
    const float* W[8];
    const float* bb[8];
    for (int c = 0; c < 8; ++c) {
        W[c]  = (const float*)d_in[8 + 2 * c];
        bb[c] = (const float*)d_in[9 + 2 * c];
    }
    const float* fcW0 = (const float*)d_in[24];
    const float* fcb0 = (const float*)d_in[25];
    const float* fcW1 = (const float*)d_in[26];
    const float* fcb1 = (const float*)d_in[27];
    const float* fcW2 = (const float*)d_in[28];
    const float* fcb2 = (const float*)d_in[29];

    int NF = in_sizes[0] / 2;
    int EF = in_sizes[4];
    int EB = in_sizes[6];

    // ---- workspace layout (floats); every segment 16B-aligned ----
    float* ws = (float*)d_ws;
    size_t p = 0;
    float* f_coeff = ws + p;  p += (size_t)EF * 16;
    float* b_coeff = ws + p;  p += (size_t)EB * 16;
    float* A1      = ws + p;  p += (size_t)NF * 96;
    float* ans2    = ws + p;  p += (size_t)NF * 64;
    int*   f_off   = (int*)(ws + p);  p += (size_t)((NF + 4) & ~3);
    int*   b_off   = (int*)(ws + p);  p += (size_t)((NF + 4) & ~3);
    float* Wt2     = ws + p;  p += 6 * 17664;   // 64 x (6*276) padded tiles
    float* Wt3     = ws + p;  p += 4 * 17664;
    float* Gbuf    = ws + p;
    size_t gBase = p;

    long wsFloats = (long)(ws_size / 4);
    long avail = wsFloats - (long)gBase;
    int chunk2 = 0, chunk3 = 0;
    if (avail > 0) {
        chunk2 = (int)((avail / 1632 < (long)NF) ? avail / 1632 : NF) & ~31;
        chunk3 = (int)((avail / 1088 < (long)NF) ? avail / 1088 : NF) & ~31;
    }
    bool bigPath = (chunk2 >= 32) && (chunk3 >= 32);

    // ---- shared prologue ----
    coeff_kernel<true><<<(EF + 255) / 256, 256, 0, stream>>>(
        (const float2*)fluidPos, fe_j, (const float2*)fluidPos, fe_i, f_coeff, EF);
    coeff_kernel<false><<<(EB + 255) / 256, 256, 0, stream>>>(
        (const float2*)boundaryPos, be_b, (const float2*)fluidPos, be_f, b_coeff, EB);
    offsets_kernel<<<(NF + 1 + 255) / 256, 256, 0, stream>>>(fe_i, EF, f_off, NF + 1);
    offsets_kernel<<<(NF + 1 + 255) / 256, 256, 0, stream>>>(be_f, EB, b_off, NF + 1);

    layer1_kernel<<<NF, 128, 0, stream>>>(fluidFeats, boundaryFeats, fcW0, fcb0,
                                          W[0], bb[0], W[1], bb[1], W[2], bb[2], W[3], bb[3],
                                          f_off, fe_j, f_coeff, b_off, be_b, b_coeff, A1);

    if (bigPath) {
        prep_kernel<<<(6 * 17664 + 255) / 256, 256, 0, stream>>>(W[4], W[5], fcW1, Wt2, 96, 6);
        prep_kernel<<<(4 * 17664 + 255) / 256, 256, 0, stream>>>(W[6], W[7], fcW2, Wt3, 64, 4);

        // layer 2: A1 (already relu'd) -> ans2
        for (int s = 0; s < NF; s += chunk2) {
            int cnt = (NF - s < chunk2) ? (NF - s) : chunk2;
            buildG_kernel<96, false><<<cnt, 256, 0, stream>>>(A1, f_off, fe_j, f_coeff, Gbuf, s);
            gemm_kernel<1632, 6, false, false><<<(cnt + 31) / 32, 256, 0, stream>>>(
                Gbuf, Wt2, bb[4], bb[5], fcb1, nullptr, ans2, s, cnt);
        }
        // layer 3: relu(ans2) -> d_out, +residual, /128
        for (int s = 0; s < NF; s += chunk3) {
            int cnt = (NF - s < chunk3) ? (NF - s) : chunk3;
            buildG_kernel<64, true><<<cnt, 256, 0, stream>>>(ans2, f_off, fe_j, f_coeff, Gbuf, s);
            gemm_kernel<1088, 4, true, true><<<(cnt + 31) / 32, 256, 0, stream>>>(
                Gbuf, Wt3, bb[6], bb[7], fcb2, ans2, (float*)d_out, s, cnt);
        }
    } else {
        conv_layer_kernel<96, false, false, false><<<NF, 256, 0, stream>>>(
            A1, W[4], bb[4], W[5], bb[5], fcW1, fcb1, f_off, fe_j, f_coeff, ans2);
        conv_layer_kernel<64, true, true, true><<<NF, 256, 0, stream>>>(
            ans2, W[6], bb[6], W[7], bb[7], fcW2, fcb2, f_off, fe_j, f_coeff, (float*)d_out);
    }
}

// Round 5
// 212.250 us; speedup vs baseline: 1.6011x; 1.6011x over previous
//
#include <hip/hip_runtime.h>
#include <math.h>

#define SUPPORT 1.5f
#define KS 4   // K-split factor for gemm

// ---------------- hat basis ----------------
__device__ __forceinline__ void hat4(float u, float h[4]) {
#pragma unroll
    for (int j = 0; j < 4; ++j) {
        float c = -1.0f + j * (2.0f / 3.0f);
        h[j] = fmaxf(0.0f, 1.0f - fabsf(u - c) * 1.5f);
    }
}

// ---------------- per-edge RBF coefficients ----------------
template <bool NEG>
__global__ void coeff_kernel(const float2* __restrict__ pa, const int* __restrict__ ia,
                             const float2* __restrict__ pb, const int* __restrict__ ib,
                             float* __restrict__ out, int E) {
    int e = blockIdx.x * blockDim.x + threadIdx.x;
    if (e >= E) return;
    float2 A = pa[ia[e]];
    float2 B = pb[ib[e]];
    float rx = (A.x - B.x) / SUPPORT;
    float ry = (A.y - B.y) / SUPPORT;
    if (NEG) { rx = -rx; ry = -ry; }
    float dx = fminf(fmaxf(rx, -1.0f), 1.0f);
    float dy = fminf(fmaxf(ry, -1.0f), 1.0f);
    float r  = sqrtf(dx * dx + dy * dy) * 2.0f - 1.0f;
    float th = atan2f(dy, dx) / 3.14159265358979323846f;
    float hr[4], ht[4];
    hat4(r, hr);
    hat4(th, ht);
    float* o = out + (size_t)e * 16;
#pragma unroll
    for (int a = 0; a < 4; ++a)
#pragma unroll
        for (int b = 0; b < 4; ++b)
            o[a * 4 + b] = hr[a] * ht[b];
}

// ---------------- CSR offsets ----------------
__global__ void offsets_kernel(const int* __restrict__ sorted, int E,
                               int* __restrict__ off, int N1) {
    int i = blockIdx.x * blockDim.x + threadIdx.x;
    if (i >= N1) return;
    int lo = 0, hi = E;
    while (lo < hi) {
        int mid = (lo + hi) >> 1;
        if (sorted[mid] < i) lo = mid + 1; else hi = mid;
    }
    off[i] = lo;
}

// ---------------- layer 1 (small Cin, direct) ----------------
__global__ void layer1_kernel(const float* __restrict__ fluidFeats,
                              const float* __restrict__ boundaryFeats,
                              const float* __restrict__ fcW0, const float* __restrict__ fcb0,
                              const float* __restrict__ W0, const float* __restrict__ b0,
                              const float* __restrict__ W1, const float* __restrict__ b1,
                              const float* __restrict__ W2, const float* __restrict__ b2,
                              const float* __restrict__ W3, const float* __restrict__ b3,
                              const int* __restrict__ f_off, const int* __restrict__ fe_j,
                              const float* __restrict__ f_coeff,
                              const int* __restrict__ b_off, const int* __restrict__ be_b,
                              const float* __restrict__ b_coeff,
                              float* __restrict__ A1) {
    int n = blockIdx.x;
    int t = threadIdx.x;
    if (t >= 96) return;
    float val;
    if (t < 32) {
        val = fluidFeats[n * 2] * fcW0[t] + fluidFeats[n * 2 + 1] * fcW0[32 + t] + fcb0[t];
    } else if (t < 64) {
        int oc = t - 32;
        const float* W = (oc < 16) ? W0 : W1;
        int o16 = oc & 15;
        float s = (oc < 16) ? b0[o16] : b1[o16];
        int e1 = f_off[n + 1];
        for (int e = f_off[n]; e < e1; ++e) {
            const float* cf = f_coeff + (size_t)e * 16;
            int srcn = fe_j[e];
            float f0 = fluidFeats[srcn * 2], f1 = fluidFeats[srcn * 2 + 1];
            float acc = 0.0f;
#pragma unroll
            for (int k = 0; k < 16; ++k)
                acc += cf[k] * (f0 * W[(k * 2 + 0) * 16 + o16] + f1 * W[(k * 2 + 1) * 16 + o16]);
            s += acc;
        }
        val = s;
    } else {
        int oc = t - 64;
        const float* W = (oc < 16) ? W2 : W3;
        int o16 = oc & 15;
        float s = (oc < 16) ? b2[o16] : b3[o16];
        int e1 = b_off[n + 1];
        for (int e = b_off[n]; e < e1; ++e) {
            const float* cf = b_coeff + (size_t)e * 16;
            int srcn = be_b[e];
            float f0 = boundaryFeats[srcn * 3], f1 = boundaryFeats[srcn * 3 + 1],
                  f2 = boundaryFeats[srcn * 3 + 2];
            float acc = 0.0f;
#pragma unroll
            for (int k = 0; k < 16; ++k)
                acc += cf[k] * (f0 * W[(k * 3 + 0) * 16 + o16] +
                                f1 * W[(k * 3 + 1) * 16 + o16] +
                                f2 * W[(k * 3 + 2) * 16 + o16]);
            s += acc;
        }
        val = s;
    }
    A1[(size_t)n * 96 + t] = fmaxf(val, 0.0f);
}

// ---------------- prep: k-major concatenated weight matrix ----------------
// Wcat[j*64 + o] = Wsrc[j][o];  j<16CIN: o<32->WA[j*32+o] else WB[j*32+o-32];
// j>=16CIN -> fcW[(j-16CIN)*64+o]
__global__ void prep_kernel(const float* __restrict__ WA, const float* __restrict__ WB,
                            const float* __restrict__ fcW, float* __restrict__ Wcat,
                            int CIN, int KTOT) {
    int idx = blockIdx.x * 256 + threadIdx.x;
    if (idx >= KTOT * 64) return;
    int j = idx >> 6, o = idx & 63;
    int KC = 16 * CIN;
    float v;
    if (j < KC) v = (o < 32) ? WA[(size_t)j * 32 + o] : WB[(size_t)j * 32 + (o - 32)];
    else        v = fcW[(size_t)(j - KC) * 64 + o];
    Wcat[idx] = v;
}

// ---------------- buildG: per-node outer-product accumulation ----------------
// G row (chunk-local) = [ sum_e coeff[e,k]*x[src,i] (k-major) | x_hat[n] ]  length KTOT=17*CIN
template <int CIN, bool RELU>
__global__ __launch_bounds__(256) void buildG_kernel(
    const float* __restrict__ X,
    const int* __restrict__ f_off, const int* __restrict__ fe_j,
    const float* __restrict__ f_coeff,
    float* __restrict__ G, int nodeBase) {
    constexpr int EPT = CIN / 16;      // 6 (CIN=96) or 4 (CIN=64)
    constexpr int KTOT = 17 * CIN;
    int n = nodeBase + blockIdx.x;
    int t = threadIdx.x;
    int k = t >> 4;
    int i0 = (t & 15) * EPT;
    float acc[EPT];
#pragma unroll
    for (int s = 0; s < EPT; ++s) acc[s] = 0.0f;
    int e0 = f_off[n], e1 = f_off[n + 1];
    for (int e = e0; e < e1; ++e) {
        int srcn = fe_j[e];
        float ck = f_coeff[(size_t)e * 16 + k];
        const float* xr = X + (size_t)srcn * CIN + i0;
#pragma unroll
        for (int s = 0; s < EPT; ++s) {
            float v = xr[s];
            if (RELU) v = fmaxf(v, 0.0f);
            acc[s] = fmaf(ck, v, acc[s]);
        }
    }
    float* grow = G + (size_t)blockIdx.x * KTOT;
#pragma unroll
    for (int s = 0; s < EPT; ++s) grow[k * CIN + i0 + s] = acc[s];
    if (t < CIN) {
        float v = X[(size_t)n * CIN + t];
        if (RELU) v = fmaxf(v, 0.0f);
        grow[16 * CIN + t] = v;
    }
}

// ---------------- gemm: K-split partial GEMM, G & W tiles in LDS ----------------
// block: 32 nodes x 64 outs x K-chunk (NSTEP steps of 68). grid (nblocks, KS).
// thread (tx=t&31, ty=t>>5): 4 nodes (4*ty..) x 2 outs (2*tx..) register tile.
// P[((ks*stride + node)*64 + o)] = partial sum.
template <int KTOT, int NSTEP>
__global__ __launch_bounds__(256) void gemm_kernel(
    const float* __restrict__ G,       // chunk-local rows, stride KTOT
    const float* __restrict__ Wcat,    // [KTOT][64] k-major
    float* __restrict__ P, int stride, int cnt) {
    __shared__ float Wl[68 * 64];      // 17408 B
    __shared__ float Gl[32 * 72];      // 9216 B (rows padded to 72)
    const int t = threadIdx.x;
    const int tx = t & 31;
    const int ty = t >> 5;
    const int nb = blockIdx.x * 32;
    const int ks = blockIdx.y;
    int k0 = ks * (NSTEP * 68);

    float a00 = 0.f, a01 = 0.f, a10 = 0.f, a11 = 0.f;
    float a20 = 0.f, a21 = 0.f, a30 = 0.f, a31 = 0.f;

    for (int st = 0; st < NSTEP; ++st, k0 += 68) {
        __syncthreads();
        // stage W tile [68][64]: 1088 float4, coalesced
        const float4* ws4 = (const float4*)(Wcat + (size_t)k0 * 64);
#pragma unroll
        for (int it = 0; it < 5; ++it) {
            int idx = it * 256 + t;
            if (idx < 1088) ((float4*)Wl)[idx] = ws4[idx];
        }
        // stage G tile [32][68] (rows padded to 72): 544 float4
#pragma unroll
        for (int it = 0; it < 3; ++it) {
            int idx = it * 256 + t;
            if (idx < 544) {
                int n = idx / 17, off = idx - n * 17;
                int gn = nb + n;
                if (gn > cnt - 1) gn = cnt - 1;
                float4 v = *(const float4*)(G + (size_t)gn * KTOT + k0 + off * 4);
                *(float4*)(Gl + n * 72 + off * 4) = v;
            }
        }
        __syncthreads();

        const float* g0p = Gl + (4 * ty + 0) * 72;
        const float* g1p = Gl + (4 * ty + 1) * 72;
        const float* g2p = Gl + (4 * ty + 2) * 72;
        const float* g3p = Gl + (4 * ty + 3) * 72;
        const float* wp  = Wl + tx * 2;
#pragma unroll 2
        for (int kk = 0; kk < 68; kk += 4) {
            float4 g0 = *(const float4*)(g0p + kk);
            float4 g1 = *(const float4*)(g1p + kk);
            float4 g2 = *(const float4*)(g2p + kk);
            float4 g3 = *(const float4*)(g3p + kk);
#define GSTEP(u, comp)                                            \
            {                                                     \
                float2 w = *(const float2*)(wp + (kk + u) * 64);  \
                a00 = fmaf(g0.comp, w.x, a00);                    \
                a01 = fmaf(g0.comp, w.y, a01);                    \
                a10 = fmaf(g1.comp, w.x, a10);                    \
                a11 = fmaf(g1.comp, w.y, a11);                    \
                a20 = fmaf(g2.comp, w.x, a20);                    \
                a21 = fmaf(g2.comp, w.y, a21);                    \
                a30 = fmaf(g3.comp, w.x, a30);                    \
                a31 = fmaf(g3.comp, w.y, a31);                    \
            }
            GSTEP(0, x) GSTEP(1, y) GSTEP(2, z) GSTEP(3, w)
#undef GSTEP
        }
    }

    float* pb = P + ((size_t)ks * stride + nb) * 64 + tx * 2;
    int rem = cnt - nb;
    if (4 * ty + 0 < rem) *(float2*)(pb + (4 * ty + 0) * 64) = make_float2(a00, a01);
    if (4 * ty + 1 < rem) *(float2*)(pb + (4 * ty + 1) * 64) = make_float2(a10, a11);
    if (4 * ty + 2 < rem) *(float2*)(pb + (4 * ty + 2) * 64) = make_float2(a20, a21);
    if (4 * ty + 3 < rem) *(float2*)(pb + (4 * ty + 3) * 64) = make_float2(a30, a31);
}

// ---------------- reduce: sum K-split partials + bias (+resid) (*1/128) ----------------
template <bool RESID, bool FINAL>
__global__ void reduce_kernel(const float* __restrict__ P, int stride,
                              const float* __restrict__ bA, const float* __restrict__ bB,
                              const float* __restrict__ fcb,
                              const float* __restrict__ Xres,
                              float* __restrict__ OUT, int nodeBase, int cnt) {
    int idx = blockIdx.x * 256 + threadIdx.x;
    if (idx >= cnt * 64) return;
    int ln = idx >> 6, o = idx & 63;
    float s = ((o < 32) ? bA[o] : bB[o - 32]) + fcb[o];
#pragma unroll
    for (int ks = 0; ks < KS; ++ks) s += P[((size_t)ks * stride + ln) * 64 + o];
    int node = nodeBase + ln;
    if (RESID) s += Xres[(size_t)node * 64 + o];
    if (FINAL) s *= (1.0f / 128.0f);
    OUT[(size_t)node * 64 + o] = s;
}

// ---------------- fallback path (round-2 kernel, proven) ----------------
template <int CIN, bool RELU_IN, bool RESIDUAL, bool FINAL>
__global__ __launch_bounds__(256) void conv_layer_kernel(
    const float* __restrict__ X,
    const float* __restrict__ WA, const float* __restrict__ bA,
    const float* __restrict__ WB, const float* __restrict__ bB,
    const float* __restrict__ fcW, const float* __restrict__ fcb,
    const int* __restrict__ f_off, const int* __restrict__ fe_j,
    const float* __restrict__ f_coeff,
    float* __restrict__ OUT) {
    constexpr int NELEM = 16 * CIN;
    constexpr int EPT = NELEM / 256;
    constexpr int BATCH = 8;
    constexpr int CHUNK = NELEM / 4;

    __shared__ float x_lds[CIN];
    __shared__ float feat[BATCH][CIN];
    __shared__ float co[BATCH][16];
    __shared__ float Gs[NELEM];
    __shared__ float red[4][64];

    int n = blockIdx.x;
    int t = threadIdx.x;

    for (int i = t; i < CIN; i += 256) {
        float v = X[(size_t)n * CIN + i];
        if (RELU_IN) v = fmaxf(v, 0.0f);
        x_lds[i] = v;
    }

    float acc[EPT];
    int kk[EPT], ii[EPT];
#pragma unroll
    for (int s = 0; s < EPT; ++s) {
        acc[s] = 0.0f;
        int j = s * 256 + t;
        kk[s] = j / CIN;
        ii[s] = j - kk[s] * CIN;
    }

    int e0 = f_off[n], e1 = f_off[n + 1];
    for (int eb = e0; eb < e1; eb += BATCH) {
        int cnt = min(BATCH, e1 - eb);
        __syncthreads();
        for (int idx = t; idx < cnt * 16; idx += 256) {
            int b = idx >> 4, c = idx & 15;
            co[b][c] = f_coeff[(size_t)(eb + b) * 16 + c];
        }
        for (int idx = t; idx < cnt * CIN; idx += 256) {
            int b = idx / CIN, i = idx - b * CIN;
            int srcn = fe_j[eb + b];
            float v = X[(size_t)srcn * CIN + i];
            if (RELU_IN) v = fmaxf(v, 0.0f);
            feat[b][i] = v;
        }
        __syncthreads();
#pragma unroll
        for (int b = 0; b < BATCH; ++b) {
            if (b >= cnt) break;
#pragma unroll
            for (int s = 0; s < EPT; ++s) acc[s] += co[b][kk[s]] * feat[b][ii[s]];
        }
    }
    __syncthreads();
#pragma unroll
    for (int s = 0; s < EPT; ++s) Gs[s * 256 + t] = acc[s];
    __syncthreads();

    int o = t & 63;
    int chunk = t >> 6;
    const float* Wp = (o < 32) ? WA : WB;
    int oc = o & 31;
    int j0 = chunk * CHUNK;
    float p0 = 0.f, p1 = 0.f, p2 = 0.f, p3 = 0.f;
    for (int j = j0; j < j0 + CHUNK; j += 4) {
        p0 += Gs[j + 0] * Wp[(size_t)(j + 0) * 32 + oc];
        p1 += Gs[j + 1] * Wp[(size_t)(j + 1) * 32 + oc];
        p2 += Gs[j + 2] * Wp[(size_t)(j + 2) * 32 + oc];
        p3 += Gs[j + 3] * Wp[(size_t)(j + 3) * 32 + oc];
    }
    red[chunk][o] = ((p0 + p1) + (p2 + p3));
    __syncthreads();
    if (t < 64) {
        float s = red[0][o] + red[1][o] + red[2][o] + red[3][o];
        s += (o < 32) ? bA[oc] : bB[oc];
        float fcv = fcb[o];
        for (int i = 0; i < CIN; ++i) fcv += x_lds[i] * fcW[i * 64 + o];
        s += fcv;
        if (RESIDUAL) s += X[(size_t)n * 64 + o];
        if (FINAL) s *= (1.0f / 128.0f);
        OUT[(size_t)n * 64 + o] = s;
    }
}

extern "C" void kernel_launch(void* const* d_in, const int* in_sizes, int n_in,
                              void* d_out, int out_size, void* d_ws, size_t ws_size,
                              hipStream_t stream) {
    const float* fluidPos      = (const float*)d_in[0];
    const float* boundaryPos   = (const float*)d_in[1];
    const float* fluidFeats    = (const float*)d_in[2];
    const float* boundaryFeats = (const float*)d_in[3];
    const int* fe_i = (const int*)d_in[4];
    const int* fe_j = (const int*)d_in[5];
    const int* be_f = (const int*)d_in[6];
    const int* be_b = (const int*)d_in[7];
    const float* W[8];
    const float* bb[8];
    for (int c = 0; c < 8; ++c) {
        W[c]  = (const float*)d_in[8 + 2 * c];
        bb[c] = (const float*)d_in[9 + 2 * c];
    }
    const float* fcW0 = (const float*)d_in[24];
    const float* fcb0 = (const float*)d_in[25];
    const float* fcW1 = (const float*)d_in[26];
    const float* fcb1 = (const float*)d_in[27];
    const float* fcW2 = (const float*)d_in[28];
    const float* fcb2 = (const float*)d_in[29];

    int NF = in_sizes[0] / 2;
    int EF = in_sizes[4];
    int EB = in_sizes[6];

    // ---- workspace layout (floats); every segment 16B-aligned ----
    float* ws = (float*)d_ws;
    size_t p = 0;
    float* f_coeff = ws + p;  p += (size_t)EF * 16;
    float* b_coeff = ws + p;  p += (size_t)EB * 16;
    float* A1      = ws + p;  p += (size_t)NF * 96;
    float* ans2    = ws + p;  p += (size_t)NF * 64;
    int*   f_off   = (int*)(ws + p);  p += (size_t)((NF + 4) & ~3);
    int*   b_off   = (int*)(ws + p);  p += (size_t)((NF + 4) & ~3);
    float* Wc2     = ws + p;  p += 1632 * 64;   // [KTOT][64] k-major
    float* Wc3     = ws + p;  p += 1088 * 64;
    float* Gbuf    = ws + p;
    size_t gBase = p;

    long wsFloats = (long)(ws_size / 4);
    long avail = wsFloats - (long)gBase;
    // per node: G row + KS partial rows of 64
    int chunk2 = 0, chunk3 = 0;
    if (avail > 0) {
        long per2 = 1632 + KS * 64, per3 = 1088 + KS * 64;
        chunk2 = (int)((avail / per2 < (long)NF) ? avail / per2 : NF) & ~31;
        chunk3 = (int)((avail / per3 < (long)NF) ? avail / per3 : NF) & ~31;
    }
    bool bigPath = (chunk2 >= 32) && (chunk3 >= 32);

    // ---- shared prologue ----
    coeff_kernel<true><<<(EF + 255) / 256, 256, 0, stream>>>(
        (const float2*)fluidPos, fe_j, (const float2*)fluidPos, fe_i, f_coeff, EF);
    coeff_kernel<false><<<(EB + 255) / 256, 256, 0, stream>>>(
        (const float2*)boundaryPos, be_b, (const float2*)fluidPos, be_f, b_coeff, EB);
    offsets_kernel<<<(NF + 1 + 255) / 256, 256, 0, stream>>>(fe_i, EF, f_off, NF + 1);
    offsets_kernel<<<(NF + 1 + 255) / 256, 256, 0, stream>>>(be_f, EB, b_off, NF + 1);

    layer1_kernel<<<NF, 128, 0, stream>>>(fluidFeats, boundaryFeats, fcW0, fcb0,
                                          W[0], bb[0], W[1], bb[1], W[2], bb[2], W[3], bb[3],
                                          f_off, fe_j, f_coeff, b_off, be_b, b_coeff, A1);

    if (bigPath) {
        prep_kernel<<<(1632 * 64 + 255) / 256, 256, 0, stream>>>(W[4], W[5], fcW1, Wc2, 96, 1632);
        prep_kernel<<<(1088 * 64 + 255) / 256, 256, 0, stream>>>(W[6], W[7], fcW2, Wc3, 64, 1088);

        // layer 2: A1 (already relu'd) -> ans2
        {
            float* Pbuf = Gbuf + (size_t)chunk2 * 1632;
            for (int s = 0; s < NF; s += chunk2) {
                int cnt = (NF - s < chunk2) ? (NF - s) : chunk2;
                int nblocks = (cnt + 31) / 32;
                buildG_kernel<96, false><<<cnt, 256, 0, stream>>>(A1, f_off, fe_j, f_coeff, Gbuf, s);
                gemm_kernel<1632, 6><<<dim3(nblocks, KS), 256, 0, stream>>>(
                    Gbuf, Wc2, Pbuf, chunk2, cnt);
                reduce_kernel<false, false><<<(cnt * 64 + 255) / 256, 256, 0, stream>>>(
                    Pbuf, chunk2, bb[4], bb[5], fcb1, nullptr, ans2, s, cnt);
            }
        }
        // layer 3: relu(ans2) -> d_out, +residual, /128
        {
            float* Pbuf = Gbuf + (size_t)chunk3 * 1088;
            for (int s = 0; s < NF; s += chunk3) {
                int cnt = (NF - s < chunk3) ? (NF - s) : chunk3;
                int nblocks = (cnt + 31) / 32;
                buildG_kernel<64, true><<<cnt, 256, 0, stream>>>(ans2, f_off, fe_j, f_coeff, Gbuf, s);
                gemm_kernel<1088, 4><<<dim3(nblocks, KS), 256, 0, stream>>>(
                    Gbuf, Wc3, Pbuf, chunk3, cnt);
                reduce_kernel<true, true><<<(cnt * 64 + 255) / 256, 256, 0, stream>>>(
                    Pbuf, chunk3, bb[6], bb[7], fcb2, ans2, (float*)d_out, s, cnt);
            }
        }
    } else {
        conv_layer_kernel<96, false, false, false><<<NF, 256, 0, stream>>>(
            A1, W[4], bb[4], W[5], bb[5], fcW1, fcb1, f_off, fe_j, f_coeff, ans2);
        conv_layer_kernel<64, true, true, true><<<NF, 256, 0, stream>>>(
            ans2, W[6], bb[6], W[7], bb[7], fcW2, fcb2, f_off, fe_j, f_coeff, (float*)d_out);
    }
}

// Round 6
// 206.467 us; speedup vs baseline: 1.6460x; 1.0280x over previous
//
#include <hip/hip_runtime.h>
#include <math.h>

#define SUPPORT 1.5f
#define KS 8   // K-split factor for gemm

// ---------------- hat basis ----------------
__device__ __forceinline__ void hat4(float u, float h[4]) {
#pragma unroll
    for (int j = 0; j < 4; ++j) {
        float c = -1.0f + j * (2.0f / 3.0f);
        h[j] = fmaxf(0.0f, 1.0f - fabsf(u - c) * 1.5f);
    }
}

// ---------------- per-edge RBF coefficients ----------------
template <bool NEG>
__global__ void coeff_kernel(const float2* __restrict__ pa, const int* __restrict__ ia,
                             const float2* __restrict__ pb, const int* __restrict__ ib,
                             float* __restrict__ out, int E) {
    int e = blockIdx.x * blockDim.x + threadIdx.x;
    if (e >= E) return;
    float2 A = pa[ia[e]];
    float2 B = pb[ib[e]];
    float rx = (A.x - B.x) / SUPPORT;
    float ry = (A.y - B.y) / SUPPORT;
    if (NEG) { rx = -rx; ry = -ry; }
    float dx = fminf(fmaxf(rx, -1.0f), 1.0f);
    float dy = fminf(fmaxf(ry, -1.0f), 1.0f);
    float r  = sqrtf(dx * dx + dy * dy) * 2.0f - 1.0f;
    float th = atan2f(dy, dx) / 3.14159265358979323846f;
    float hr[4], ht[4];
    hat4(r, hr);
    hat4(th, ht);
    float* o = out + (size_t)e * 16;
#pragma unroll
    for (int a = 0; a < 4; ++a)
#pragma unroll
        for (int b = 0; b < 4; ++b)
            o[a * 4 + b] = hr[a] * ht[b];
}

// ---------------- CSR offsets ----------------
__global__ void offsets_kernel(const int* __restrict__ sorted, int E,
                               int* __restrict__ off, int N1) {
    int i = blockIdx.x * blockDim.x + threadIdx.x;
    if (i >= N1) return;
    int lo = 0, hi = E;
    while (lo < hi) {
        int mid = (lo + hi) >> 1;
        if (sorted[mid] < i) lo = mid + 1; else hi = mid;
    }
    off[i] = lo;
}

// ---------------- layer 1 (small Cin, direct) ----------------
__global__ void layer1_kernel(const float* __restrict__ fluidFeats,
                              const float* __restrict__ boundaryFeats,
                              const float* __restrict__ fcW0, const float* __restrict__ fcb0,
                              const float* __restrict__ W0, const float* __restrict__ b0,
                              const float* __restrict__ W1, const float* __restrict__ b1,
                              const float* __restrict__ W2, const float* __restrict__ b2,
                              const float* __restrict__ W3, const float* __restrict__ b3,
                              const int* __restrict__ f_off, const int* __restrict__ fe_j,
                              const float* __restrict__ f_coeff,
                              const int* __restrict__ b_off, const int* __restrict__ be_b,
                              const float* __restrict__ b_coeff,
                              float* __restrict__ A1) {
    int n = blockIdx.x;
    int t = threadIdx.x;
    if (t >= 96) return;
    float val;
    if (t < 32) {
        val = fluidFeats[n * 2] * fcW0[t] + fluidFeats[n * 2 + 1] * fcW0[32 + t] + fcb0[t];
    } else if (t < 64) {
        int oc = t - 32;
        const float* W = (oc < 16) ? W0 : W1;
        int o16 = oc & 15;
        float s = (oc < 16) ? b0[o16] : b1[o16];
        int e1 = f_off[n + 1];
        for (int e = f_off[n]; e < e1; ++e) {
            const float* cf = f_coeff + (size_t)e * 16;
            int srcn = fe_j[e];
            float f0 = fluidFeats[srcn * 2], f1 = fluidFeats[srcn * 2 + 1];
            float acc = 0.0f;
#pragma unroll
            for (int k = 0; k < 16; ++k)
                acc += cf[k] * (f0 * W[(k * 2 + 0) * 16 + o16] + f1 * W[(k * 2 + 1) * 16 + o16]);
            s += acc;
        }
        val = s;
    } else {
        int oc = t - 64;
        const float* W = (oc < 16) ? W2 : W3;
        int o16 = oc & 15;
        float s = (oc < 16) ? b2[o16] : b3[o16];
        int e1 = b_off[n + 1];
        for (int e = b_off[n]; e < e1; ++e) {
            const float* cf = b_coeff + (size_t)e * 16;
            int srcn = be_b[e];
            float f0 = boundaryFeats[srcn * 3], f1 = boundaryFeats[srcn * 3 + 1],
                  f2 = boundaryFeats[srcn * 3 + 2];
            float acc = 0.0f;
#pragma unroll
            for (int k = 0; k < 16; ++k)
                acc += cf[k] * (f0 * W[(k * 3 + 0) * 16 + o16] +
                                f1 * W[(k * 3 + 1) * 16 + o16] +
                                f2 * W[(k * 3 + 2) * 16 + o16]);
            s += acc;
        }
        val = s;
    }
    A1[(size_t)n * 96 + t] = fmaxf(val, 0.0f);
}

// ---------------- prep: k-major concatenated weight matrix ----------------
__global__ void prep_kernel(const float* __restrict__ WA, const float* __restrict__ WB,
                            const float* __restrict__ fcW, float* __restrict__ Wcat,
                            int CIN, int KTOT) {
    int idx = blockIdx.x * 256 + threadIdx.x;
    if (idx >= KTOT * 64) return;
    int j = idx >> 6, o = idx & 63;
    int KC = 16 * CIN;
    float v;
    if (j < KC) v = (o < 32) ? WA[(size_t)j * 32 + o] : WB[(size_t)j * 32 + (o - 32)];
    else        v = fcW[(size_t)(j - KC) * 64 + o];
    Wcat[idx] = v;
}

// ---------------- buildG v2: 4-wide edge unroll with masked tail ----------------
// G row (chunk-local) = [ sum_e coeff[e,k]*x[src,i] (k-major) | x_hat[n] ]  length 17*CIN
template <int CIN, bool RELU>
__global__ __launch_bounds__(256) void buildG_kernel(
    const float* __restrict__ X,
    const int* __restrict__ f_off, const int* __restrict__ fe_j,
    const float* __restrict__ f_coeff,
    float* __restrict__ G, int nodeBase) {
    constexpr int EPT = CIN / 16;      // 6 (CIN=96) or 4 (CIN=64)
    constexpr int KTOT = 17 * CIN;
    int n = nodeBase + blockIdx.x;
    int t = threadIdx.x;
    int k = t >> 4;
    int i0 = (t & 15) * EPT;
    float acc[EPT];
#pragma unroll
    for (int s = 0; s < EPT; ++s) acc[s] = 0.0f;

    int e0 = f_off[n], e1 = f_off[n + 1];
    for (int e = e0; e < e1; e += 4) {
        // clamped indices + zero-masked coeffs -> uniform 4-wide iterations, no OOB
        int ea = e;
        int eb = (e + 1 < e1) ? e + 1 : e;
        int ec = (e + 2 < e1) ? e + 2 : e;
        int ed = (e + 3 < e1) ? e + 3 : e;
        int s0 = fe_j[ea], s1 = fe_j[eb], s2 = fe_j[ec], s3 = fe_j[ed];
        float c0 = f_coeff[(size_t)ea * 16 + k];
        float c1 = f_coeff[(size_t)eb * 16 + k];
        float c2 = f_coeff[(size_t)ec * 16 + k];
        float c3 = f_coeff[(size_t)ed * 16 + k];
        c1 = (e + 1 < e1) ? c1 : 0.0f;
        c2 = (e + 2 < e1) ? c2 : 0.0f;
        c3 = (e + 3 < e1) ? c3 : 0.0f;
        const float* x0 = X + (size_t)s0 * CIN + i0;
        const float* x1 = X + (size_t)s1 * CIN + i0;
        const float* x2 = X + (size_t)s2 * CIN + i0;
        const float* x3 = X + (size_t)s3 * CIN + i0;
        float v0[EPT], v1[EPT], v2[EPT], v3[EPT];
#pragma unroll
        for (int s = 0; s < EPT; ++s) v0[s] = x0[s];
#pragma unroll
        for (int s = 0; s < EPT; ++s) v1[s] = x1[s];
#pragma unroll
        for (int s = 0; s < EPT; ++s) v2[s] = x2[s];
#pragma unroll
        for (int s = 0; s < EPT; ++s) v3[s] = x3[s];
        if (RELU) {
#pragma unroll
            for (int s = 0; s < EPT; ++s) {
                v0[s] = fmaxf(v0[s], 0.0f);
                v1[s] = fmaxf(v1[s], 0.0f);
                v2[s] = fmaxf(v2[s], 0.0f);
                v3[s] = fmaxf(v3[s], 0.0f);
            }
        }
#pragma unroll
        for (int s = 0; s < EPT; ++s) {
            acc[s] = fmaf(c0, v0[s], acc[s]);
            acc[s] = fmaf(c1, v1[s], acc[s]);
            acc[s] = fmaf(c2, v2[s], acc[s]);
            acc[s] = fmaf(c3, v3[s], acc[s]);
        }
    }

    float* grow = G + (size_t)blockIdx.x * KTOT;
#pragma unroll
    for (int s = 0; s < EPT; ++s) grow[k * CIN + i0 + s] = acc[s];
    if (t < CIN) {
        float v = X[(size_t)n * CIN + t];
        if (RELU) v = fmaxf(v, 0.0f);
        grow[16 * CIN + t] = v;
    }
}

// ---------------- gemm: K-split partial GEMM, G & W tiles in LDS ----------------
// block: 32 nodes x 64 outs x K-chunk (NSTEP steps of 68). grid (nblocks, KS).
template <int KTOT, int NSTEP>
__global__ __launch_bounds__(256) void gemm_kernel(
    const float* __restrict__ G,       // chunk-local rows, stride KTOT
    const float* __restrict__ Wcat,    // [KTOT][64] k-major
    float* __restrict__ P, int stride, int cnt) {
    __shared__ float Wl[68 * 64];
    __shared__ float Gl[32 * 72];
    const int t = threadIdx.x;
    const int tx = t & 31;
    const int ty = t >> 5;
    const int nb = blockIdx.x * 32;
    const int ks = blockIdx.y;
    int k0 = ks * (NSTEP * 68);

    float a00 = 0.f, a01 = 0.f, a10 = 0.f, a11 = 0.f;
    float a20 = 0.f, a21 = 0.f, a30 = 0.f, a31 = 0.f;

    for (int st = 0; st < NSTEP; ++st, k0 += 68) {
        __syncthreads();
        const float4* ws4 = (const float4*)(Wcat + (size_t)k0 * 64);
#pragma unroll
        for (int it = 0; it < 5; ++it) {
            int idx = it * 256 + t;
            if (idx < 1088) ((float4*)Wl)[idx] = ws4[idx];
        }
#pragma unroll
        for (int it = 0; it < 3; ++it) {
            int idx = it * 256 + t;
            if (idx < 544) {
                int n = idx / 17, off = idx - n * 17;
                int gn = nb + n;
                if (gn > cnt - 1) gn = cnt - 1;
                float4 v = *(const float4*)(G + (size_t)gn * KTOT + k0 + off * 4);
                *(float4*)(Gl + n * 72 + off * 4) = v;
            }
        }
        __syncthreads();

        const float* g0p = Gl + (4 * ty + 0) * 72;
        const float* g1p = Gl + (4 * ty + 1) * 72;
        const float* g2p = Gl + (4 * ty + 2) * 72;
        const float* g3p = Gl + (4 * ty + 3) * 72;
        const float* wp  = Wl + tx * 2;
#pragma unroll 2
        for (int kk = 0; kk < 68; kk += 4) {
            float4 g0 = *(const float4*)(g0p + kk);
            float4 g1 = *(const float4*)(g1p + kk);
            float4 g2 = *(const float4*)(g2p + kk);
            float4 g3 = *(const float4*)(g3p + kk);
#define GSTEP(u, comp)                                            \
            {                                                     \
                float2 w = *(const float2*)(wp + (kk + u) * 64);  \
                a00 = fmaf(g0.comp, w.x, a00);                    \
                a01 = fmaf(g0.comp, w.y, a01);                    \
                a10 = fmaf(g1.comp, w.x, a10);                    \
                a11 = fmaf(g1.comp, w.y, a11);                    \
                a20 = fmaf(g2.comp, w.x, a20);                    \
                a21 = fmaf(g2.comp, w.y, a21);                    \
                a30 = fmaf(g3.comp, w.x, a30);                    \
                a31 = fmaf(g3.comp, w.y, a31);                    \
            }
            GSTEP(0, x) GSTEP(1, y) GSTEP(2, z) GSTEP(3, w)
#undef GSTEP
        }
    }

    float* pb = P + ((size_t)ks * stride + nb) * 64 + tx * 2;
    int rem = cnt - nb;
    if (4 * ty + 0 < rem) *(float2*)(pb + (4 * ty + 0) * 64) = make_float2(a00, a01);
    if (4 * ty + 1 < rem) *(float2*)(pb + (4 * ty + 1) * 64) = make_float2(a10, a11);
    if (4 * ty + 2 < rem) *(float2*)(pb + (4 * ty + 2) * 64) = make_float2(a20, a21);
    if (4 * ty + 3 < rem) *(float2*)(pb + (4 * ty + 3) * 64) = make_float2(a30, a31);
}

// ---------------- reduce: sum K-split partials + bias (+resid) (*1/128) ----------------
template <bool RESID, bool FINAL>
__global__ void reduce_kernel(const float* __restrict__ P, int stride,
                              const float* __restrict__ bA, const float* __restrict__ bB,
                              const float* __restrict__ fcb,
                              const float* __restrict__ Xres,
                              float* __restrict__ OUT, int nodeBase, int cnt) {
    int idx = blockIdx.x * 256 + threadIdx.x;
    if (idx >= cnt * 64) return;
    int ln = idx >> 6, o = idx & 63;
    float s = ((o < 32) ? bA[o] : bB[o - 32]) + fcb[o];
#pragma unroll
    for (int ks = 0; ks < KS; ++ks) s += P[((size_t)ks * stride + ln) * 64 + o];
    int node = nodeBase + ln;
    if (RESID) s += Xres[(size_t)node * 64 + o];
    if (FINAL) s *= (1.0f / 128.0f);
    OUT[(size_t)node * 64 + o] = s;
}

// ---------------- fallback path (round-2 kernel, proven) ----------------
template <int CIN, bool RELU_IN, bool RESIDUAL, bool FINAL>
__global__ __launch_bounds__(256) void conv_layer_kernel(
    const float* __restrict__ X,
    const float* __restrict__ WA, const float* __restrict__ bA,
    const float* __restrict__ WB, const float* __restrict__ bB,
    const float* __restrict__ fcW, const float* __restrict__ fcb,
    const int* __restrict__ f_off, const int* __restrict__ fe_j,
    const float* __restrict__ f_coeff,
    float* __restrict__ OUT) {
    constexpr int NELEM = 16 * CIN;
    constexpr int EPT = NELEM / 256;
    constexpr int BATCH = 8;
    constexpr int CHUNK = NELEM / 4;

    __shared__ float x_lds[CIN];
    __shared__ float feat[BATCH][CIN];
    __shared__ float co[BATCH][16];
    __shared__ float Gs[NELEM];
    __shared__ float red[4][64];

    int n = blockIdx.x;
    int t = threadIdx.x;

    for (int i = t; i < CIN; i += 256) {
        float v = X[(size_t)n * CIN + i];
        if (RELU_IN) v = fmaxf(v, 0.0f);
        x_lds[i] = v;
    }

    float acc[EPT];
    int kk[EPT], ii[EPT];
#pragma unroll
    for (int s = 0; s < EPT; ++s) {
        acc[s] = 0.0f;
        int j = s * 256 + t;
        kk[s] = j / CIN;
        ii[s] = j - kk[s] * CIN;
    }

    int e0 = f_off[n], e1 = f_off[n + 1];
    for (int eb = e0; eb < e1; eb += BATCH) {
        int cnt = min(BATCH, e1 - eb);
        __syncthreads();
        for (int idx = t; idx < cnt * 16; idx += 256) {
            int b = idx >> 4, c = idx & 15;
            co[b][c] = f_coeff[(size_t)(eb + b) * 16 + c];
        }
        for (int idx = t; idx < cnt * CIN; idx += 256) {
            int b = idx / CIN, i = idx - b * CIN;
            int srcn = fe_j[eb + b];
            float v = X[(size_t)srcn * CIN + i];
            if (RELU_IN) v = fmaxf(v, 0.0f);
            feat[b][i] = v;
        }
        __syncthreads();
#pragma unroll
        for (int b = 0; b < BATCH; ++b) {
            if (b >= cnt) break;
#pragma unroll
            for (int s = 0; s < EPT; ++s) acc[s] += co[b][kk[s]] * feat[b][ii[s]];
        }
    }
    __syncthreads();
#pragma unroll
    for (int s = 0; s < EPT; ++s) Gs[s * 256 + t] = acc[s];
    __syncthreads();

    int o = t & 63;
    int chunk = t >> 6;
    const float* Wp = (o < 32) ? WA : WB;
    int oc = o & 31;
    int j0 = chunk * CHUNK;
    float p0 = 0.f, p1 = 0.f, p2 = 0.f, p3 = 0.f;
    for (int j = j0; j < j0 + CHUNK; j += 4) {
        p0 += Gs[j + 0] * Wp[(size_t)(j + 0) * 32 + oc];
        p1 += Gs[j + 1] * Wp[(size_t)(j + 1) * 32 + oc];
        p2 += Gs[j + 2] * Wp[(size_t)(j + 2) * 32 + oc];
        p3 += Gs[j + 3] * Wp[(size_t)(j + 3) * 32 + oc];
    }
    red[chunk][o] = ((p0 + p1) + (p2 + p3));
    __syncthreads();
    if (t < 64) {
        float s = red[0][o] + red[1][o] + red[2][o] + red[3][o];
        s += (o < 32) ? bA[oc] : bB[oc];
        float fcv = fcb[o];
        for (int i = 0; i < CIN; ++i) fcv += x_lds[i] * fcW[i * 64 + o];
        s += fcv;
        if (RESIDUAL) s += X[(size_t)n * 64 + o];
        if (FINAL) s *= (1.0f / 128.0f);
        OUT[(size_t)n * 64 + o] = s;
    }
}

extern "C" void kernel_launch(void* const* d_in, const int* in_sizes, int n_in,
                              void* d_out, int out_size, void* d_ws, size_t ws_size,
                              hipStream_t stream) {
    const float* fluidPos      = (const float*)d_in[0];
    const float* boundaryPos   = (const float*)d_in[1];
    const float* fluidFeats    = (const float*)d_in[2];
    const float* boundaryFeats = (const float*)d_in[3];
    const int* fe_i = (const int*)d_in[4];
    const int* fe_j = (const int*)d_in[5];
    const int* be_f = (const int*)d_in[6];
    const int* be_b = (const int*)d_in[7];
    const float* W[8];
    const float* bb[8];
    for (int c = 0; c < 8; ++c) {
        W[c]  = (const float*)d_in[8 + 2 * c];
        bb[c] = (const float*)d_in[9 + 2 * c];
    }
    const float* fcW0 = (const float*)d_in[24];
    const float* fcb0 = (const float*)d_in[25];
    const float* fcW1 = (const float*)d_in[26];
    const float* fcb1 = (const float*)d_in[27];
    const float* fcW2 = (const float*)d_in[28];
    const float* fcb2 = (const float*)d_in[29];

    int NF = in_sizes[0] / 2;
    int EF = in_sizes[4];
    int EB = in_sizes[6];

    // ---- workspace layout (floats); every segment 16B-aligned ----
    float* ws = (float*)d_ws;
    size_t p = 0;
    float* f_coeff = ws + p;  p += (size_t)EF * 16;
    float* b_coeff = ws + p;  p += (size_t)EB * 16;
    float* A1      = ws + p;  p += (size_t)NF * 96;
    float* ans2    = ws + p;  p += (size_t)NF * 64;
    int*   f_off   = (int*)(ws + p);  p += (size_t)((NF + 4) & ~3);
    int*   b_off   = (int*)(ws + p);  p += (size_t)((NF + 4) & ~3);
    float* Wc2     = ws + p;  p += 1632 * 64;   // [KTOT][64] k-major
    float* Wc3     = ws + p;  p += 1088 * 64;
    float* Gbuf    = ws + p;
    size_t gBase = p;

    long wsFloats = (long)(ws_size / 4);
    long avail = wsFloats - (long)gBase;
    int chunk2 = 0, chunk3 = 0;
    if (avail > 0) {
        long per2 = 1632 + KS * 64, per3 = 1088 + KS * 64;
        chunk2 = (int)((avail / per2 < (long)NF) ? avail / per2 : NF) & ~31;
        chunk3 = (int)((avail / per3 < (long)NF) ? avail / per3 : NF) & ~31;
    }
    bool bigPath = (chunk2 >= 32) && (chunk3 >= 32);

    // ---- shared prologue ----
    coeff_kernel<true><<<(EF + 255) / 256, 256, 0, stream>>>(
        (const float2*)fluidPos, fe_j, (const float2*)fluidPos, fe_i, f_coeff, EF);
    coeff_kernel<false><<<(EB + 255) / 256, 256, 0, stream>>>(
        (const float2*)boundaryPos, be_b, (const float2*)fluidPos, be_f, b_coeff, EB);
    offsets_kernel<<<(NF + 1 + 255) / 256, 256, 0, stream>>>(fe_i, EF, f_off, NF + 1);
    offsets_kernel<<<(NF + 1 + 255) / 256, 256, 0, stream>>>(be_f, EB, b_off, NF + 1);

    layer1_kernel<<<NF, 128, 0, stream>>>(fluidFeats, boundaryFeats, fcW0, fcb0,
                                          W[0], bb[0], W[1], bb[1], W[2], bb[2], W[3], bb[3],
                                          f_off, fe_j, f_coeff, b_off, be_b, b_coeff, A1);

    if (bigPath) {
        prep_kernel<<<(1632 * 64 + 255) / 256, 256, 0, stream>>>(W[4], W[5], fcW1, Wc2, 96, 1632);
        prep_kernel<<<(1088 * 64 + 255) / 256, 256, 0, stream>>>(W[6], W[7], fcW2, Wc3, 64, 1088);

        // layer 2: A1 (already relu'd) -> ans2
        {
            float* Pbuf = Gbuf + (size_t)chunk2 * 1632;
            for (int s = 0; s < NF; s += chunk2) {
                int cnt = (NF - s < chunk2) ? (NF - s) : chunk2;
                int nblocks = (cnt + 31) / 32;
                buildG_kernel<96, false><<<cnt, 256, 0, stream>>>(A1, f_off, fe_j, f_coeff, Gbuf, s);
                gemm_kernel<1632, 3><<<dim3(nblocks, KS), 256, 0, stream>>>(
                    Gbuf, Wc2, Pbuf, chunk2, cnt);
                reduce_kernel<false, false><<<(cnt * 64 + 255) / 256, 256, 0, stream>>>(
                    Pbuf, chunk2, bb[4], bb[5], fcb1, nullptr, ans2, s, cnt);
            }
        }
        // layer 3: relu(ans2) -> d_out, +residual, /128
        {
            float* Pbuf = Gbuf + (size_t)chunk3 * 1088;
            for (int s = 0; s < NF; s += chunk3) {
                int cnt = (NF - s < chunk3) ? (NF - s) : chunk3;
                int nblocks = (cnt + 31) / 32;
                buildG_kernel<64, true><<<cnt, 256, 0, stream>>>(ans2, f_off, fe_j, f_coeff, Gbuf, s);
                gemm_kernel<1088, 2><<<dim3(nblocks, KS), 256, 0, stream>>>(
                    Gbuf, Wc3, Pbuf, chunk3, cnt);
                reduce_kernel<true, true><<<(cnt * 64 + 255) / 256, 256, 0, stream>>>(
                    Pbuf, chunk3, bb[6], bb[7], fcb2, ans2, (float*)d_out, s, cnt);
            }
        }
    } else {
        conv_layer_kernel<96, false, false, false><<<NF, 256, 0, stream>>>(
            A1, W[4], bb[4], W[5], bb[5], fcW1, fcb1, f_off, fe_j, f_coeff, ans2);
        conv_layer_kernel<64, true, true, true><<<NF, 256, 0, stream>>>(
            ans2, W[6], bb[6], W[7], bb[7], fcW2, fcb2, f_off, fe_j, f_coeff, (float*)d_out);
    }
}